// Round 1
// baseline (599.615 us; speedup 1.0000x reference)
//
#include <hip/hip_runtime.h>
#include <hip/hip_bf16.h>

// Problem constants (fixed by reference)
#define BSZ   64          // image batch
#define NWIN  64          // windows per image
#define PSZ   49          // patch size (7x7)
#define DIM   96
#define NHEAD 8
#define HDIM  12
#define BTOT  4096        // BSZ*NWIN
#define ROWS  200704      // BTOT*PSZ
#define NEGV  (-1000000.0f)

#define OUT_ELEMS   19267584     // 64*64*49*96
// att follows out in d_out: 32768*49*49 floats

// ws layout (bytes)
#define WT_FLOATS   27648        // WT [96][288]
#define WOT_FLOATS  9216         // WoT [96][96]
#define KQV_OFF     147456       // (27648+9216)*4, bf16 kqv [ROWS][288]
#define OBUF_OFF    (KQV_OFF + (size_t)ROWS*288*2)  // f32 o [ROWS][96]

static __device__ __forceinline__ unsigned f2bf_pack(float a, float b) {
    union { float f; unsigned u; } x, y; x.f = a; y.f = b;
    unsigned lo = (x.u + 0x7FFFu + ((x.u >> 16) & 1u)) >> 16;
    unsigned hi = (y.u + 0x7FFFu + ((y.u >> 16) & 1u)) >> 16;
    return (lo & 0xFFFFu) | (hi << 16);
}
static __device__ __forceinline__ float bf2f(unsigned s) {
    union { unsigned u; float f; } v; v.u = s << 16; return v.f;
}
static __device__ __forceinline__ void load12bf(const unsigned short* p, float* f) {
    const uint2* p2 = (const uint2*)p;
    uint2 a = p2[0], b = p2[1], c = p2[2];
    f[0]=bf2f(a.x&0xFFFFu); f[1]=bf2f(a.x>>16); f[2]=bf2f(a.y&0xFFFFu); f[3]=bf2f(a.y>>16);
    f[4]=bf2f(b.x&0xFFFFu); f[5]=bf2f(b.x>>16); f[6]=bf2f(b.y&0xFFFFu); f[7]=bf2f(b.y>>16);
    f[8]=bf2f(c.x&0xFFFFu); f[9]=bf2f(c.x>>16); f[10]=bf2f(c.y&0xFFFFu); f[11]=bf2f(c.y>>16);
}

// ---------------- prep: transpose weights ----------------
__global__ void prep_transpose(const float* __restrict__ Wk,
                               const float* __restrict__ Wo,
                               float* __restrict__ ws) {
    int i = blockIdx.x * 256 + threadIdx.x;
    if (i < WT_FLOATS) {
        int d = i / 288, f = i % 288;
        ws[i] = Wk[f * 96 + d];
    }
    int j = i - WT_FLOATS;
    if (j >= 0 && j < WOT_FLOATS) {
        int d = j / 96, f = j % 96;
        ws[WT_FLOATS + j] = Wo[f * 96 + d];
    }
}

// ---------------- K1: shift-gather + kqv GEMM ----------------
// grid 3136, block 384. 64 rows x 288 feats per block; thread tile 4x12.
__global__ __launch_bounds__(384) void k1_kqv(
        const float* __restrict__ window,
        const float* __restrict__ b_kqv,
        const float* __restrict__ wsf,
        unsigned short* __restrict__ kqv) {
    __shared__ __align__(16) float xt[64][96];
    const float* WT = wsf;  // [96][288]
    const int t = threadIdx.x;
    const int blk = blockIdx.x;

    // gather 64 rows (shifted-window input) into LDS
#pragma unroll
    for (int i = 0; i < 4; ++i) {
        int idx = t + i * 384;            // < 1536
        int r = idx / 24, c4 = idx % 24;
        int R = blk * 64 + r;
        int b = R / 49, p = R - b * 49;
        int bb = b >> 6, n = b & 63;
        int s = n * 49 + p;
        int y = s / 56, xx = s - y * 56;
        int ys = y + 53;  if (ys >= 56) ys -= 56;
        int xs = xx + 53; if (xs >= 56) xs -= 56;
        int sn = (ys / 7) * 8 + (xs / 7);
        int sp = (ys % 7) * 7 + (xs % 7);
        const float4* src = (const float4*)(window + (((size_t)(bb * 64 + sn)) * 49 + sp) * 96) + c4;
        *(float4*)&xt[r][c4 * 4] = *src;
    }
    __syncthreads();

    const int rg = t / 24, cg = t - (t / 24) * 24;   // rg 0..15, cg 0..23
    const int r0 = rg * 4, f0 = cg * 12;

    float acc[4][12];
#pragma unroll
    for (int i = 0; i < 4; ++i)
#pragma unroll
        for (int j = 0; j < 12; ++j) acc[i][j] = b_kqv[f0 + j];

#pragma unroll 4
    for (int d4 = 0; d4 < 24; ++d4) {
        float4 xa[4];
#pragma unroll
        for (int i = 0; i < 4; ++i) xa[i] = *(const float4*)&xt[r0 + i][d4 * 4];
#pragma unroll
        for (int dd = 0; dd < 4; ++dd) {
            const float* wrow = WT + (d4 * 4 + dd) * 288 + f0;
            float4 w0 = *(const float4*)(wrow);
            float4 w1 = *(const float4*)(wrow + 4);
            float4 w2 = *(const float4*)(wrow + 8);
#pragma unroll
            for (int i = 0; i < 4; ++i) {
                float xv = ((const float*)&xa[i])[dd];
                acc[i][0] += xv * w0.x; acc[i][1] += xv * w0.y;
                acc[i][2] += xv * w0.z; acc[i][3] += xv * w0.w;
                acc[i][4] += xv * w1.x; acc[i][5] += xv * w1.y;
                acc[i][6] += xv * w1.z; acc[i][7] += xv * w1.w;
                acc[i][8] += xv * w2.x; acc[i][9] += xv * w2.y;
                acc[i][10] += xv * w2.z; acc[i][11] += xv * w2.w;
            }
        }
    }

#pragma unroll
    for (int i = 0; i < 4; ++i) {
        size_t R = (size_t)blk * 64 + r0 + i;
        unsigned short* dst = kqv + R * 288 + f0;
        unsigned u0 = f2bf_pack(acc[i][0], acc[i][1]);
        unsigned u1 = f2bf_pack(acc[i][2], acc[i][3]);
        unsigned u2 = f2bf_pack(acc[i][4], acc[i][5]);
        unsigned u3 = f2bf_pack(acc[i][6], acc[i][7]);
        unsigned u4 = f2bf_pack(acc[i][8], acc[i][9]);
        unsigned u5 = f2bf_pack(acc[i][10], acc[i][11]);
        *(uint2*)(dst)     = make_uint2(u0, u1);
        *(uint2*)(dst + 4) = make_uint2(u2, u3);
        *(uint2*)(dst + 8) = make_uint2(u4, u5);
    }
}

// ---------------- K2: attention per (b,h) ----------------
// grid 32768, block 64 (1 wave). lane = query row p.
__global__ __launch_bounds__(64) void k2_attn(
        const unsigned short* __restrict__ kqv,
        float* __restrict__ att_out,
        float* __restrict__ obuf) {
    const int bh = blockIdx.x;
    const int b = bh >> 3, h = bh & 7;
    const int lane = threadIdx.x;

    __shared__ float kk[49][12];
    __shared__ float vv[49][12];
    __shared__ int wv[49];

    if (lane < 49) {
        const unsigned short* base = kqv + ((size_t)(b * 49 + lane)) * 288 + h * 12;
        float tmp[12];
        load12bf(base, tmp);                 // k
#pragma unroll
        for (int j = 0; j < 12; ++j) kk[lane][j] = tmp[j];
        load12bf(base + 192, tmp);           // v
#pragma unroll
        for (int j = 0; j < 12; ++j) vv[lane][j] = tmp[j];

        // faithful mask window id: m = bh % 64
        int m = bh & 63;
        int wi = m >> 3, wj = m & 7;
        int pi = lane / 7, pj = lane % 7;
        int y = wi * 7 + pi, x = wj * 7 + pj;
        int ys = y + 53; if (ys >= 56) ys -= 56;
        int xs = x + 53; if (xs >= 56) xs -= 56;
        wv[lane] = (ys / 7) * 8 + (xs / 7);
    }
    __syncthreads();

    if (lane < 49) {
        const unsigned short* qbase = kqv + ((size_t)(b * 49 + lane)) * 288 + 96 + h * 12;
        float q[12];
        load12bf(qbase, q);

        const float scale = 0.2886751345948129f;  // 1/sqrt(12)
        float lg[49];
        float mx = -1e30f;
        const int wp = wv[lane];
#pragma unroll
        for (int r = 0; r < 49; ++r) {
            float s = 0.0f;
#pragma unroll
            for (int j = 0; j < 12; ++j) s += q[j] * kk[r][j];
            s *= scale;
            if (wv[r] != wp) s += NEGV;
            lg[r] = s;
            mx = fmaxf(mx, s);
        }
        float sum = 0.0f;
#pragma unroll
        for (int r = 0; r < 49; ++r) {
            float e = expf(lg[r] - mx);
            lg[r] = e;
            sum += e;
        }
        const float inv = 1.0f / sum;

        float o[12];
#pragma unroll
        for (int j = 0; j < 12; ++j) o[j] = 0.0f;

        float* ab = att_out + (size_t)bh * 2401 + lane * 49;
#pragma unroll
        for (int r = 0; r < 49; ++r) {
            float a = lg[r] * inv;
            ab[r] = a;
#pragma unroll
            for (int j = 0; j < 12; ++j) o[j] += a * vv[r][j];
        }

        float* op = obuf + ((size_t)(b * 49 + lane)) * 96 + h * 12;
        *(float4*)(op)     = make_float4(o[0], o[1], o[2], o[3]);
        *(float4*)(op + 4) = make_float4(o[4], o[5], o[6], o[7]);
        *(float4*)(op + 8) = make_float4(o[8], o[9], o[10], o[11]);
    }
}

// ---------------- K3: inverse-shift gather + output projection ----------------
// grid 1568, block 512. 128 rows x 96 feats per block; thread tile 4x6.
__global__ __launch_bounds__(512) void k3_proj(
        const float* __restrict__ obuf,
        const float* __restrict__ wsf,
        const float* __restrict__ b_out,
        float* __restrict__ out) {
    __shared__ __align__(16) float ot[128][96];  // 48 KB
    const float* WoT = wsf + WT_FLOATS;  // [96][96]
    const int t = threadIdx.x;
    const int blk = blockIdx.x;

#pragma unroll
    for (int i = 0; i < 6; ++i) {
        int idx = t + i * 512;            // < 3072
        int r = idx / 24, c4 = idx % 24;
        int R = blk * 128 + r;
        int bb = R / 3136, s2 = R - bb * 3136;
        int y2 = s2 / 56, x2 = s2 - y2 * 56;
        int ys = y2 + 4; if (ys >= 56) ys -= 56;
        int xs = x2 + 4; if (xs >= 56) xs -= 56;
        int sn = (ys / 7) * 8 + (xs / 7);
        int sp = (ys % 7) * 7 + (xs % 7);
        const float4* src = (const float4*)(obuf + (((size_t)(bb * 64 + sn)) * 49 + sp) * 96) + c4;
        *(float4*)&ot[r][c4 * 4] = *src;
    }
    __syncthreads();

    const int rg = t / 16, cg = t - (t / 16) * 16;  // rg 0..31, cg 0..15
    const int r0 = rg * 4, f0 = cg * 6;

    float acc[4][6];
#pragma unroll
    for (int i = 0; i < 4; ++i)
#pragma unroll
        for (int j = 0; j < 6; ++j) acc[i][j] = b_out[f0 + j];

#pragma unroll 4
    for (int d4 = 0; d4 < 24; ++d4) {
        float4 xa[4];
#pragma unroll
        for (int i = 0; i < 4; ++i) xa[i] = *(const float4*)&ot[r0 + i][d4 * 4];
#pragma unroll
        for (int dd = 0; dd < 4; ++dd) {
            const float* wrow = WoT + (d4 * 4 + dd) * 96 + f0;
            float2 w0 = *(const float2*)(wrow);
            float2 w1 = *(const float2*)(wrow + 2);
            float2 w2 = *(const float2*)(wrow + 4);
#pragma unroll
            for (int i = 0; i < 4; ++i) {
                float xv = ((const float*)&xa[i])[dd];
                acc[i][0] += xv * w0.x; acc[i][1] += xv * w0.y;
                acc[i][2] += xv * w1.x; acc[i][3] += xv * w1.y;
                acc[i][4] += xv * w2.x; acc[i][5] += xv * w2.y;
            }
        }
    }

#pragma unroll
    for (int i = 0; i < 4; ++i) {
        size_t R = (size_t)blk * 128 + r0 + i;
        float* dst = out + R * 96 + f0;
        *(float2*)(dst)     = make_float2(acc[i][0], acc[i][1]);
        *(float2*)(dst + 2) = make_float2(acc[i][2], acc[i][3]);
        *(float2*)(dst + 4) = make_float2(acc[i][4], acc[i][5]);
    }
}

extern "C" void kernel_launch(void* const* d_in, const int* in_sizes, int n_in,
                              void* d_out, int out_size, void* d_ws, size_t ws_size,
                              hipStream_t stream) {
    const float* window = (const float*)d_in[0];
    const float* W_kqv  = (const float*)d_in[1];
    const float* b_kqv  = (const float*)d_in[2];
    const float* W_out  = (const float*)d_in[3];
    const float* b_out  = (const float*)d_in[4];

    float* out = (float*)d_out;
    float* att = out + OUT_ELEMS;

    float* wsf = (float*)d_ws;
    unsigned short* kqv = (unsigned short*)((char*)d_ws + KQV_OFF);
    float* obuf = (float*)((char*)d_ws + OBUF_OFF);

    prep_transpose<<<144, 256, 0, stream>>>(W_kqv, W_out, wsf);
    k1_kqv<<<3136, 384, 0, stream>>>(window, b_kqv, wsf, kqv);
    k2_attn<<<32768, 64, 0, stream>>>(kqv, att, obuf);
    k3_proj<<<1568, 512, 0, stream>>>(obuf, wsf, b_out, out);
}

// Round 2
// 283.742 us; speedup vs baseline: 2.1132x; 2.1132x over previous
//
#include <hip/hip_runtime.h>
#include <hip/hip_bf16.h>

// Problem constants
#define BSZ   64
#define NWIN  64
#define PSZ   49
#define DIM   96
#define NHEAD 8
#define HDIM  12
#define BTOT  4096
#define ROWS  200704
#define NEGV  (-1000000.0f)

#define OUT_ELEMS   19267584     // 64*64*49*96 (att follows in d_out)

// ws layout (bytes):
//  [0)        packed bf16 B-fragments: Wb1 27648 ushorts, Wb2 9216 ushorts
//  [73728)    kqv bf16 [ROWS][288]  = 115,605,504 B
//  [...]      obuf bf16 [ROWS][96]  =  38,535,168 B
#define WB2_USH     27648
#define KQV_OFF_B   73728
#define OBUF_OFF_B  (73728 + (size_t)ROWS*288*2)

typedef __bf16 bf16x8 __attribute__((ext_vector_type(8)));
typedef float  f32x4  __attribute__((ext_vector_type(4)));

static __device__ __forceinline__ unsigned short f2bf(float a) {
    union { float f; unsigned u; } x; x.f = a;
    return (unsigned short)((x.u + 0x7FFFu + ((x.u >> 16) & 1u)) >> 16);
}
static __device__ __forceinline__ unsigned f2bf_pack(float a, float b) {
    return (unsigned)f2bf(a) | ((unsigned)f2bf(b) << 16);
}
static __device__ __forceinline__ float bf2f(unsigned s) {
    union { unsigned u; float f; } v; v.u = s << 16; return v.f;
}
static __device__ __forceinline__ bf16x8 as_bf16x8(uint4 u) {
    union { uint4 u; bf16x8 b; } x; x.u = u; return x.b;
}
static __device__ __forceinline__ void load12bf(const unsigned short* p, float* f) {
    const uint2* p2 = (const uint2*)p;
    uint2 a = p2[0], b = p2[1], c = p2[2];
    f[0]=bf2f(a.x&0xFFFFu); f[1]=bf2f(a.x>>16); f[2]=bf2f(a.y&0xFFFFu); f[3]=bf2f(a.y>>16);
    f[4]=bf2f(b.x&0xFFFFu); f[5]=bf2f(b.x>>16); f[6]=bf2f(b.y&0xFFFFu); f[7]=bf2f(b.y>>16);
    f[8]=bf2f(c.x&0xFFFFu); f[9]=bf2f(c.x>>16); f[10]=bf2f(c.y&0xFFFFu); f[11]=bf2f(c.y>>16);
}

// ---------------- prep: pack weights into MFMA B-fragment layout (bf16) ----------------
__global__ void prep_pack(const float* __restrict__ Wk,
                          const float* __restrict__ Wo,
                          unsigned short* __restrict__ wb) {
    int i = blockIdx.x * 256 + threadIdx.x;   // 0..36863
    if (i < WB2_USH) {
        int j = i & 7, l = (i >> 3) & 63, nk = i >> 9;     // nk = nt*3+ks
        int nt = nk / 3, ks = nk - nt * 3;
        int n = nt * 16 + (l & 15);
        int k = ks * 32 + ((l >> 4) << 3) + j;
        wb[i] = f2bf(Wk[n * 96 + k]);
    } else if (i < 36864) {
        int r = i - WB2_USH;
        int j = r & 7, l = (r >> 3) & 63, nk = r >> 9;
        int nt = nk / 3, ks = nk - nt * 3;
        int n = nt * 16 + (l & 15);
        int k = ks * 32 + ((l >> 4) << 3) + j;
        wb[i] = f2bf(Wo[n * 96 + k]);
    }
}

// ---------------- K1: shift-gather + kqv GEMM (MFMA bf16) ----------------
__global__ __launch_bounds__(256) void k1_kqv(
        const float* __restrict__ window,
        const float* __restrict__ b_kqv,
        const unsigned short* __restrict__ wb1,
        unsigned short* __restrict__ kqv) {
    __shared__ unsigned short xt[64][104];
    __shared__ unsigned short ckq[64 * 296];
    const int t = threadIdx.x, blk = blockIdx.x;

#pragma unroll
    for (int i = 0; i < 6; ++i) {
        int idx = t + i * 256;
        int r = idx / 24, c4 = idx % 24;
        int R = blk * 64 + r;
        int b = R / 49, p = R - b * 49;
        int bb = b >> 6, n = b & 63;
        int s = n * 49 + p;
        int y = s / 56, xx = s - y * 56;
        int ys = y + 53;  if (ys >= 56) ys -= 56;
        int xs = xx + 53; if (xs >= 56) xs -= 56;
        int sn = (ys / 7) * 8 + (xs / 7);
        int sp = (ys % 7) * 7 + (xs % 7);
        float4 v = *((const float4*)(window + (((size_t)(bb * 64 + sn)) * 49 + sp) * 96) + c4);
        *(uint2*)&xt[r][c4 * 4] = make_uint2(f2bf_pack(v.x, v.y), f2bf_pack(v.z, v.w));
    }
    __syncthreads();

    const int w = t >> 6, l = t & 63;
    const int lr = l & 15, lg4 = l >> 4;

    bf16x8 a[3];
#pragma unroll
    for (int ks = 0; ks < 3; ++ks)
        a[ks] = as_bf16x8(*(const uint4*)&xt[w * 16 + lr][ks * 32 + lg4 * 8]);

#pragma unroll
    for (int nt = 0; nt < 18; ++nt) {
        float bias = b_kqv[nt * 16 + lr];
        f32x4 acc = {bias, bias, bias, bias};
#pragma unroll
        for (int ks = 0; ks < 3; ++ks) {
            bf16x8 bf = as_bf16x8(*(const uint4*)(wb1 + (size_t)((nt * 3 + ks) * 64 + l) * 8));
            acc = __builtin_amdgcn_mfma_f32_16x16x32_bf16(a[ks], bf, acc, 0, 0, 0);
        }
        int col = nt * 16 + lr;
#pragma unroll
        for (int reg = 0; reg < 4; ++reg) {
            int row = w * 16 + lg4 * 4 + reg;
            ckq[row * 296 + col] = f2bf(acc[reg]);
        }
    }
    __syncthreads();

#pragma unroll
    for (int i = 0; i < 9; ++i) {
        int idx = t + i * 256;
        int r = idx / 36, c = idx % 36;
        uint4 v = *(const uint4*)&ckq[r * 296 + c * 8];
        *(uint4*)(kqv + ((size_t)(blk * 64 + r)) * 288 + c * 8) = v;
    }
}

// ---------------- K2: attention per (b,h) ----------------
__global__ __launch_bounds__(64) void k2_attn(
        const unsigned short* __restrict__ kqv,
        float* __restrict__ att_out,
        unsigned short* __restrict__ obuf) {
    const int bh = blockIdx.x;
    const int b = bh >> 3, h = bh & 7;
    const int lane = threadIdx.x;

    __shared__ float kk[49][12];
    __shared__ float vv[49][12];
    __shared__ int wv[49];
    __shared__ float att_s[2401];

    if (lane < 49) {
        const unsigned short* base = kqv + ((size_t)(b * 49 + lane)) * 288 + h * 12;
        float tmp[12];
        load12bf(base, tmp);
#pragma unroll
        for (int j = 0; j < 12; ++j) kk[lane][j] = tmp[j];
        load12bf(base + 192, tmp);
#pragma unroll
        for (int j = 0; j < 12; ++j) vv[lane][j] = tmp[j];

        int m = bh & 63;
        int wi = m >> 3, wj = m & 7;
        int pi = lane / 7, pj = lane % 7;
        int y = wi * 7 + pi, x = wj * 7 + pj;
        int ys = y + 53; if (ys >= 56) ys -= 56;
        int xs = x + 53; if (xs >= 56) xs -= 56;
        wv[lane] = (ys / 7) * 8 + (xs / 7);
    }
    __syncthreads();

    if (lane < 49) {
        const unsigned short* qbase = kqv + ((size_t)(b * 49 + lane)) * 288 + 96 + h * 12;
        float q[12];
        load12bf(qbase, q);

        const float scale = 0.2886751345948129f;
        float lg[49];
        float mx = -1e30f;
        const int wp = wv[lane];
#pragma unroll
        for (int r = 0; r < 49; ++r) {
            float s = 0.0f;
#pragma unroll
            for (int j = 0; j < 12; ++j) s += q[j] * kk[r][j];
            s *= scale;
            if (wv[r] != wp) s += NEGV;
            lg[r] = s;
            mx = fmaxf(mx, s);
        }
        float sum = 0.0f;
#pragma unroll
        for (int r = 0; r < 49; ++r) {
            float e = expf(lg[r] - mx);
            lg[r] = e;
            sum += e;
        }
        const float inv = 1.0f / sum;

        float o[12];
#pragma unroll
        for (int j = 0; j < 12; ++j) o[j] = 0.0f;
#pragma unroll
        for (int r = 0; r < 49; ++r) {
            float a = lg[r] * inv;
            att_s[lane * 49 + r] = a;
#pragma unroll
            for (int j = 0; j < 12; ++j) o[j] += a * vv[r][j];
        }

        unsigned short* op = obuf + ((size_t)(b * 49 + lane)) * 96 + h * 12;
        *(uint2*)(op)     = make_uint2(f2bf_pack(o[0], o[1]), f2bf_pack(o[2], o[3]));
        *(uint2*)(op + 4) = make_uint2(f2bf_pack(o[4], o[5]), f2bf_pack(o[6], o[7]));
        *(uint2*)(op + 8) = make_uint2(f2bf_pack(o[8], o[9]), f2bf_pack(o[10], o[11]));
    }
    __syncthreads();

    float* ab = att_out + (size_t)bh * 2401;
#pragma unroll
    for (int i = 0; i < 38; ++i) {
        int idx = lane + i * 64;
        if (idx < 2401) ab[idx] = att_s[idx];
    }
}

// ---------------- K3: inverse-shift gather + output projection (MFMA bf16) ----------------
__global__ __launch_bounds__(256) void k3_proj(
        const unsigned short* __restrict__ obuf,
        const unsigned short* __restrict__ wb2,
        const float* __restrict__ b_out,
        float* __restrict__ out) {
    __shared__ unsigned short xt[64][104];
    __shared__ float ot[64 * 100];
    const int t = threadIdx.x, blk = blockIdx.x;

#pragma unroll
    for (int i = 0; i < 3; ++i) {
        int idx = t + i * 256;
        int r = idx / 12, c = idx % 12;
        int R = blk * 64 + r;
        int bb = R / 3136, s2 = R - bb * 3136;
        int y2 = s2 / 56, x2 = s2 - y2 * 56;
        int ys = y2 + 4; if (ys >= 56) ys -= 56;
        int xs = x2 + 4; if (xs >= 56) xs -= 56;
        int sn = (ys / 7) * 8 + (xs / 7);
        int sp = (ys % 7) * 7 + (xs % 7);
        uint4 v = *((const uint4*)(obuf + ((size_t)(bb * 64 + sn) * 49 + sp) * 96) + c);
        *(uint4*)&xt[r][c * 8] = v;
    }
    __syncthreads();

    const int w = t >> 6, l = t & 63;
    const int lr = l & 15, lg4 = l >> 4;

    bf16x8 a[3];
#pragma unroll
    for (int ks = 0; ks < 3; ++ks)
        a[ks] = as_bf16x8(*(const uint4*)&xt[w * 16 + lr][ks * 32 + lg4 * 8]);

#pragma unroll
    for (int nt = 0; nt < 6; ++nt) {
        float bias = b_out[nt * 16 + lr];
        f32x4 acc = {bias, bias, bias, bias};
#pragma unroll
        for (int ks = 0; ks < 3; ++ks) {
            bf16x8 bf = as_bf16x8(*(const uint4*)(wb2 + (size_t)((nt * 3 + ks) * 64 + l) * 8));
            acc = __builtin_amdgcn_mfma_f32_16x16x32_bf16(a[ks], bf, acc, 0, 0, 0);
        }
        int col = nt * 16 + lr;
#pragma unroll
        for (int reg = 0; reg < 4; ++reg) {
            int row = w * 16 + lg4 * 4 + reg;
            ot[row * 100 + col] = acc[reg];
        }
    }
    __syncthreads();

#pragma unroll
    for (int i = 0; i < 6; ++i) {
        int idx = t + i * 256;
        int r = idx / 24, c = idx % 24;
        float4 v = *(const float4*)&ot[r * 100 + c * 4];
        *(float4*)(out + ((size_t)(blk * 64 + r)) * 96 + c * 4) = v;
    }
}

extern "C" void kernel_launch(void* const* d_in, const int* in_sizes, int n_in,
                              void* d_out, int out_size, void* d_ws, size_t ws_size,
                              hipStream_t stream) {
    const float* window = (const float*)d_in[0];
    const float* W_kqv  = (const float*)d_in[1];
    const float* b_kqv  = (const float*)d_in[2];
    const float* W_out  = (const float*)d_in[3];
    const float* b_out  = (const float*)d_in[4];

    float* out = (float*)d_out;
    float* att = out + OUT_ELEMS;

    unsigned short* wb   = (unsigned short*)d_ws;
    unsigned short* kqv  = (unsigned short*)((char*)d_ws + KQV_OFF_B);
    unsigned short* obuf = (unsigned short*)((char*)d_ws + OBUF_OFF_B);

    prep_pack<<<144, 256, 0, stream>>>(W_kqv, W_out, wb);
    k1_kqv<<<3136, 256, 0, stream>>>(window, b_kqv, wb, kqv);
    k2_attn<<<32768, 64, 0, stream>>>(kqv, att, obuf);
    k3_proj<<<3136, 256, 0, stream>>>(obuf, wb + WB2_USH, b_out, out);
}

// Round 3
// 245.791 us; speedup vs baseline: 2.4395x; 1.1544x over previous
//
#include <hip/hip_runtime.h>
#include <hip/hip_bf16.h>

// Problem constants
#define NEGV  (-1000000.0f)
#define OUT_ELEMS   19267584     // 64*64*49*96 (att follows in d_out)
#define ROWS  200704

// ws layout (bytes):
//  [0)      packed bf16 B-fragments: Wb1 27648 ushorts, Wb2 9216 ushorts
//  [73728)  obuf bf16 [ROWS][96] = 38,535,168 B
#define WB2_USH     27648
#define OBUF_OFF_B  73728

typedef __bf16 bf16x8 __attribute__((ext_vector_type(8)));
typedef __bf16 bf16x2 __attribute__((ext_vector_type(2)));
typedef float  f32x4  __attribute__((ext_vector_type(4)));

static __device__ __forceinline__ unsigned short f2bf(float a) {
    union { float f; unsigned u; } x; x.f = a;
    return (unsigned short)((x.u + 0x7FFFu + ((x.u >> 16) & 1u)) >> 16);
}
static __device__ __forceinline__ unsigned f2bf_pack(float a, float b) {
    return (unsigned)f2bf(a) | ((unsigned)f2bf(b) << 16);
}
static __device__ __forceinline__ bf16x8 as_bf16x8(uint4 u) {
    union { uint4 u; bf16x8 b; } x; x.u = u; return x.b;
}

// packed bf16x2 dot product: a.x*b.x + a.y*b.y + c
#if __has_builtin(__builtin_amdgcn_fdot2_f32_bf16)
static __device__ __forceinline__ float dot2bf(unsigned a, unsigned b, float c) {
    union { unsigned u; bf16x2 v; } x, y; x.u = a; y.u = b;
    return __builtin_amdgcn_fdot2_f32_bf16(x.v, y.v, c, false);
}
#else
static __device__ __forceinline__ float dot2bf(unsigned a, unsigned b, float c) {
    union { unsigned u; float f; } al, ah, bl, bh;
    al.u = a << 16; ah.u = a & 0xFFFF0000u;
    bl.u = b << 16; bh.u = b & 0xFFFF0000u;
    return c + al.f * bl.f + ah.f * bh.f;
}
#endif

// ---------------- prep: pack weights into MFMA B-fragment layout (bf16) ----------------
__global__ void prep_pack(const float* __restrict__ Wk,
                          const float* __restrict__ Wo,
                          unsigned short* __restrict__ wb) {
    int i = blockIdx.x * 256 + threadIdx.x;   // 0..36863
    if (i < WB2_USH) {
        int j = i & 7, l = (i >> 3) & 63, nk = i >> 9;     // nk = nt*3+ks
        int nt = nk / 3, ks = nk - nt * 3;
        int n = nt * 16 + (l & 15);
        int k = ks * 32 + ((l >> 4) << 3) + j;
        wb[i] = f2bf(Wk[n * 96 + k]);
    } else if (i < 36864) {
        int r = i - WB2_USH;
        int j = r & 7, l = (r >> 3) & 63, nk = r >> 9;
        int nt = nk / 3, ks = nk - nt * 3;
        int n = nt * 16 + (l & 15);
        int k = ks * 32 + ((l >> 4) << 3) + j;
        wb[i] = f2bf(Wo[n * 96 + k]);
    }
}

// ---------------- K12: fused shift-gather + kqv GEMM + attention ----------------
// One block per b (grid 4096, 512 threads = 8 waves). Wave h = head h in attn phase.
__global__ __launch_bounds__(512) void k12(
        const float* __restrict__ window,
        const float* __restrict__ b_kqv,
        const unsigned short* __restrict__ wb1,
        float* __restrict__ att_out,
        unsigned short* __restrict__ obuf) {
    __shared__ unsigned short xt[64 * 104];   // bf16 x tile, rows 49-63 zero pad
    __shared__ unsigned short ckq[49 * 196];  // bf16 k (cols 0-95) + q (96-191)
    __shared__ unsigned short vt[96 * 52];    // bf16 V^T: row (12h+d), col r (0..48)
    __shared__ int wv_s[8 * 52];              // window ids per head

    const int t = threadIdx.x, b = blockIdx.x;
    const int w = t >> 6, l = t & 63;

    // zero xt pad rows (49..63): 15*104 us = 780 dwords
    {
        unsigned* z = (unsigned*)(xt + 49 * 104);
        for (int i = t; i < 780; i += 512) z[i] = 0;
    }
    // gather + cvt 49 rows x 96 f32 (shifted-window input)
    const int bimg = b >> 6, n = b & 63;
    for (int idx = t; idx < 1176; idx += 512) {
        int r = idx / 24, c4 = idx % 24;
        int s = n * 49 + r;
        int y = s / 56, x = s - y * 56;
        int ys = y + 53; if (ys >= 56) ys -= 56;
        int xs = x + 53; if (xs >= 56) xs -= 56;
        int sn = (ys / 7) * 8 + (xs / 7);
        int sp = (ys % 7) * 7 + (xs % 7);
        float4 v = *((const float4*)(window + ((size_t)(bimg * 64 + sn) * 49 + sp) * 96) + c4);
        *(uint2*)&xt[r * 104 + c4 * 4] = make_uint2(f2bf_pack(v.x, v.y), f2bf_pack(v.z, v.w));
    }
    // window-id table for head w (faithful mask: m = (b*8+h) % 64)
    if (l < 49) {
        int m = ((b << 3) + w) & 63;
        int wi = m >> 3, wj = m & 7;
        int pi = l / 7, pj = l % 7;
        int y = wi * 7 + pi, x = wj * 7 + pj;
        int ys = y + 53; if (ys >= 56) ys -= 56;
        int xs = x + 53; if (xs >= 56) xs -= 56;
        wv_s[w * 52 + l] = (ys / 7) * 8 + (xs / 7);
    }
    // zero vt pad cols (49..51) so the (lg[48], 0)*garbage pair can't make NaN
    for (int i = t; i < 288; i += 512) {
        int cc = i / 3, e = 49 + i % 3;
        vt[cc * 52 + e] = 0;
    }
    __syncthreads();

    // ---- kqv GEMM: wave w -> m-tile (w&3), nt range (w>>2)*9 .. +8 ----
    const int lr = l & 15, lg4 = l >> 4;
    const int mt = w & 3, nh = w >> 2;

    bf16x8 a[3];
#pragma unroll
    for (int ks = 0; ks < 3; ++ks)
        a[ks] = as_bf16x8(*(const uint4*)&xt[(mt * 16 + lr) * 104 + ks * 32 + lg4 * 8]);

#pragma unroll
    for (int j = 0; j < 9; ++j) {
        int nt = nh * 9 + j;
        float bias = b_kqv[nt * 16 + lr];
        f32x4 acc = {bias, bias, bias, bias};
#pragma unroll
        for (int ks = 0; ks < 3; ++ks) {
            bf16x8 bf = as_bf16x8(*(const uint4*)(wb1 + ((size_t)(nt * 3 + ks) * 64 + l) * 8));
            acc = __builtin_amdgcn_mfma_f32_16x16x32_bf16(a[ks], bf, acc, 0, 0, 0);
        }
        int col = nt * 16 + lr;
        if (nt < 12) {            // k and q columns -> ckq
#pragma unroll
            for (int reg = 0; reg < 4; ++reg) {
                int R = mt * 16 + lg4 * 4 + reg;
                if (R < 49) ckq[R * 196 + col] = f2bf(acc[reg]);
            }
        } else {                  // v columns -> transposed vt
            int cc = col - 192;
#pragma unroll
            for (int reg = 0; reg < 4; ++reg) {
                int R = mt * 16 + lg4 * 4 + reg;
                if (R < 49) vt[cc * 52 + R] = f2bf(acc[reg]);
            }
        }
    }
    __syncthreads();

    // ---- attention: wave h = head h, lane p = query row ----
    if (l < 49) {
        const int h = w, p = l;
        const unsigned* qp = (const unsigned*)&ckq[p * 196 + 96 + h * 12];
        unsigned qd0 = qp[0], qd1 = qp[1], qd2 = qp[2], qd3 = qp[3], qd4 = qp[4], qd5 = qp[5];
        const int wp = wv_s[h * 52 + p];

        float lg[49];
        float mx = -3.0e38f;
#pragma unroll
        for (int r = 0; r < 49; ++r) {
            const unsigned* kp = (const unsigned*)&ckq[r * 196 + h * 12];
            float s = 0.0f;
            s = dot2bf(qd0, kp[0], s);
            s = dot2bf(qd1, kp[1], s);
            s = dot2bf(qd2, kp[2], s);
            s = dot2bf(qd3, kp[3], s);
            s = dot2bf(qd4, kp[4], s);
            s = dot2bf(qd5, kp[5], s);
            s *= 0.2886751345948129f;
            if (wv_s[h * 52 + r] != wp) s += NEGV;
            lg[r] = s;
            mx = fmaxf(mx, s);
        }
        float sum = 0.0f;
#pragma unroll
        for (int r = 0; r < 49; ++r) {
            float e = __expf(lg[r] - mx);
            lg[r] = e;
            sum += e;
        }
        const float inv = 1.0f / sum;

        float* ab = att_out + ((size_t)((b << 3) + h)) * 2401 + p * 49;
#pragma unroll
        for (int r = 0; r < 49; ++r) {
            float aa = lg[r] * inv;
            lg[r] = aa;
            ab[r] = aa;
        }

        // pack P to bf16 pairs
        unsigned pk[25];
#pragma unroll
        for (int i = 0; i < 24; ++i) pk[i] = f2bf_pack(lg[2 * i], lg[2 * i + 1]);
        pk[24] = f2bf_pack(lg[48], 0.0f);

        // PV via V^T rows (wave-uniform broadcast reads)
        float o[12];
#pragma unroll
        for (int d = 0; d < 12; ++d) {
            const unsigned* vp = (const unsigned*)&vt[(h * 12 + d) * 52];
            float acc = 0.0f;
#pragma unroll
            for (int i = 0; i < 25; ++i) acc = dot2bf(pk[i], vp[i], acc);
            o[d] = acc;
        }
        unsigned short* op = obuf + ((size_t)(b * 49 + p)) * 96 + h * 12;
        *(uint2*)(op)     = make_uint2(f2bf_pack(o[0], o[1]), f2bf_pack(o[2], o[3]));
        *(uint2*)(op + 4) = make_uint2(f2bf_pack(o[4], o[5]), f2bf_pack(o[6], o[7]));
        *(uint2*)(op + 8) = make_uint2(f2bf_pack(o[8], o[9]), f2bf_pack(o[10], o[11]));
    }
}

// ---------------- K3: inverse-shift gather + output projection (MFMA bf16) ----------------
__global__ __launch_bounds__(256) void k3_proj(
        const unsigned short* __restrict__ obuf,
        const unsigned short* __restrict__ wb2,
        const float* __restrict__ b_out,
        float* __restrict__ out) {
    __shared__ unsigned short xt[64][104];
    __shared__ float ot[64 * 100];
    const int t = threadIdx.x, blk = blockIdx.x;

#pragma unroll
    for (int i = 0; i < 3; ++i) {
        int idx = t + i * 256;
        int r = idx / 12, c = idx % 12;
        int R = blk * 64 + r;
        int bb = R / 3136, s2 = R - bb * 3136;
        int y2 = s2 / 56, x2 = s2 - y2 * 56;
        int ys = y2 + 4; if (ys >= 56) ys -= 56;
        int xs = x2 + 4; if (xs >= 56) xs -= 56;
        int sn = (ys / 7) * 8 + (xs / 7);
        int sp = (ys % 7) * 7 + (xs % 7);
        uint4 v = *((const uint4*)(obuf + ((size_t)(bb * 64 + sn) * 49 + sp) * 96) + c);
        *(uint4*)&xt[r][c * 8] = v;
    }
    __syncthreads();

    const int w = t >> 6, l = t & 63;
    const int lr = l & 15, lg4 = l >> 4;

    bf16x8 a[3];
#pragma unroll
    for (int ks = 0; ks < 3; ++ks)
        a[ks] = as_bf16x8(*(const uint4*)&xt[w * 16 + lr][ks * 32 + lg4 * 8]);

#pragma unroll
    for (int nt = 0; nt < 6; ++nt) {
        float bias = b_out[nt * 16 + lr];
        f32x4 acc = {bias, bias, bias, bias};
#pragma unroll
        for (int ks = 0; ks < 3; ++ks) {
            bf16x8 bf = as_bf16x8(*(const uint4*)(wb2 + (size_t)((nt * 3 + ks) * 64 + l) * 8));
            acc = __builtin_amdgcn_mfma_f32_16x16x32_bf16(a[ks], bf, acc, 0, 0, 0);
        }
        int col = nt * 16 + lr;
#pragma unroll
        for (int reg = 0; reg < 4; ++reg) {
            int row = w * 16 + lg4 * 4 + reg;
            ot[row * 100 + col] = acc[reg];
        }
    }
    __syncthreads();

#pragma unroll
    for (int i = 0; i < 6; ++i) {
        int idx = t + i * 256;
        int r = idx / 24, c = idx % 24;
        float4 v = *(const float4*)&ot[r * 100 + c * 4];
        *(float4*)(out + ((size_t)(blk * 64 + r)) * 96 + c * 4) = v;
    }
}

extern "C" void kernel_launch(void* const* d_in, const int* in_sizes, int n_in,
                              void* d_out, int out_size, void* d_ws, size_t ws_size,
                              hipStream_t stream) {
    const float* window = (const float*)d_in[0];
    const float* W_kqv  = (const float*)d_in[1];
    const float* b_kqv  = (const float*)d_in[2];
    const float* W_out  = (const float*)d_in[3];
    const float* b_out  = (const float*)d_in[4];

    float* out = (float*)d_out;
    float* att = out + OUT_ELEMS;

    unsigned short* wb   = (unsigned short*)d_ws;
    unsigned short* obuf = (unsigned short*)((char*)d_ws + OBUF_OFF_B);

    prep_pack<<<144, 256, 0, stream>>>(W_kqv, W_out, wb);
    k12<<<4096, 512, 0, stream>>>(window, b_kqv, wb, att, obuf);
    k3_proj<<<3136, 256, 0, stream>>>(obuf, wb + WB2_USH, b_out, out);
}